// Round 1
// baseline (7596.099 us; speedup 1.0000x reference)
//
#include <hip/hip_runtime.h>

#define QD 256   // states
#define SD 128   // symbols
#define BD 1024  // batch
#define TD 128   // time steps
#define NC 4     // column chunks per symbol
#define CPC 64   // columns per chunk

typedef __bf16 bf16x8 __attribute__((ext_vector_type(8)));
typedef float floatx4 __attribute__((ext_vector_type(4)));

__device__ inline unsigned short f32_to_bf16(float f) {
  union { float f; unsigned u; } v; v.f = f;
  unsigned u = v.u + 0x7fffu + ((v.u >> 16) & 1u);  // round-to-nearest-even
  return (unsigned short)(u >> 16);
}

// K1: repack A[qf][s][qt] -> Wrep in per-(symbol,chunk) MFMA B-fragment order.
// W = exp(A)/256 (the 1/256 per-step rescale is folded in; out += T*ln(256)).
// Fragment order per (s,c): element ((kb*4+quad)*64 + n)*8 + j  holds
// W[k = kb*32+quad*8+j][n_global = c*64+n]  — so the main kernel's ds_read_b128
// per lane is perfectly linear and bank-conflict-free.
__global__ void k_repack(const float* __restrict__ A, unsigned short* __restrict__ Wrep) {
  __shared__ float tile[32][QD];
  const int bid = blockIdx.x;
  const int s = bid >> 3, kb = bid & 7;
  const int tid = threadIdx.x;
  for (int r = 0; r < 32; ++r)
    tile[r][tid] = A[(size_t)(kb * 32 + r) * (SD * QD) + (size_t)s * QD + tid];
  __syncthreads();
  for (int g = tid; g < 1024; g += 256) {
    const int c = g >> 8, quad = (g >> 6) & 3, n = g & 63;
    unsigned short out8[8];
#pragma unroll
    for (int j = 0; j < 8; ++j) {
      float v = __expf(tile[quad * 8 + j][c * 64 + n]) * 0.00390625f;
      out8[j] = f32_to_bf16(v);
    }
    size_t off = (size_t)(s * NC + c) * 16384 + (size_t)((kb * 4 + quad) * 64 + n) * 8;
    *(uint4*)(Wrep + off) = *(uint4*)out8;
  }
}

// K2: P0 rows = broadcast(init) in bf16 (alpha0 = log(init) -> P = init), zero flags.
__global__ void k_init(const float* __restrict__ init, unsigned short* __restrict__ P0,
                       unsigned* __restrict__ flags) {
  const int i = blockIdx.x * 256 + threadIdx.x;   // grid covers max(BD*QD, TD*BD)
  if (i < BD * QD) P0[i] = f32_to_bf16(init[i & (QD - 1)]);
  if (i < TD * BD) flags[i] = 0u;
}

// K3: per-timestep counting sort of batch indices by symbol (xs is static input).
__global__ void k_sort(const int* __restrict__ xs, unsigned* __restrict__ order,
                       unsigned* __restrict__ start, unsigned* __restrict__ count) {
  __shared__ unsigned hist[SD];
  __shared__ unsigned cur[SD];
  const int t = blockIdx.x, tid = threadIdx.x;
  if (tid < SD) hist[tid] = 0u;
  __syncthreads();
  int sym[4];
  for (int r = 0; r < 4; ++r) {
    const int b = tid + 256 * r;
    sym[r] = xs[(size_t)b * TD + t];
    atomicAdd(&hist[sym[r]], 1u);
  }
  __syncthreads();
  if (tid == 0) {
    unsigned acc = 0;
    for (int s2 = 0; s2 < SD; ++s2) {
      cur[s2] = acc; start[t * SD + s2] = acc; count[t * SD + s2] = hist[s2];
      acc += hist[s2];
    }
  }
  __syncthreads();
  for (int r = 0; r < 4; ++r) {
    const int b = tid + 256 * r;
    const unsigned pos = atomicAdd(&cur[sym[r]], 1u);
    order[(size_t)t * BD + pos] = (unsigned)b;
  }
}

// K4: cooperative dataflow forward. 512 blocks = (symbol, n-chunk). Each block
// holds its 32KB W chunk in LDS for all 128 steps. Rows flow between blocks via
// double-buffered global P (bf16) gated by per-row flags (4 chunk-producers each).
// The flag chain serializes buffer reuse: writing buf slot (t+1)&1 for row b at
// step t happens only after flags[t-1][b]=4, which happens only after the step
// t-1 producer finished READING that same slot. No grid barrier needed.
__global__ void __launch_bounds__(256, 2) k_fwd(
    const unsigned short* __restrict__ Wrep,
    unsigned short* __restrict__ Pa, unsigned short* __restrict__ Pb,
    unsigned* __restrict__ flags,
    const unsigned* __restrict__ order, const unsigned* __restrict__ start,
    const unsigned* __restrict__ count) {
  __shared__ unsigned short Wlds[16384];  // 32 KB
  const int bid = blockIdx.x;
  const int sid = bid >> 2, c = bid & 3;
  const int tid = threadIdx.x;
  const int wave = tid >> 6, lane = tid & 63;
  const int quad = lane >> 4, lcol = lane & 15;

  {
    const uint4* src = (const uint4*)(Wrep + (size_t)(sid * NC + c) * 16384);
    uint4* dst = (uint4*)Wlds;
    for (int i = tid; i < 2048; i += 256) dst[i] = src[i];
  }
  __syncthreads();

  unsigned short* bufs[2] = {Pa, Pb};

  for (int t = 0; t < TD; ++t) {
    const unsigned cnt = count[t * SD + sid];
    const unsigned st = start[t * SD + sid];
    const unsigned short* Pc = bufs[t & 1];
    unsigned short* Pn = bufs[(t + 1) & 1];
    const unsigned* ordt = order + (size_t)t * BD;

    for (unsigned mt = 0; mt * 16u < cnt; ++mt) {
      const unsigned ridx = mt * 16u + (unsigned)lcol;
      const unsigned aidx = (ridx < cnt) ? ridx : 0u;  // clamp: OOB lanes compute garbage, not stored
      const unsigned b_a = ordt[st + aidx];

      if (t > 0) {  // wait until all 4 column-chunk producers of step t-1 wrote row b_a
        unsigned* fl = flags + (size_t)(t - 1) * BD + b_a;
        while (true) {
          unsigned f = __hip_atomic_load(fl, __ATOMIC_RELAXED, __HIP_MEMORY_SCOPE_AGENT);
          if (__ballot(f < 4u) == 0ull) break;
          __builtin_amdgcn_s_sleep(1);
        }
        __builtin_amdgcn_fence(__ATOMIC_ACQUIRE, "agent");
      }

      // A-fragments: lane holds P[row=lcol][k=kb*32+quad*8+j], 16B per kb
      uint4 araw[8];
      const uint4* prow = (const uint4*)(Pc + (size_t)b_a * QD);
#pragma unroll
      for (int kb = 0; kb < 8; ++kb) araw[kb] = prow[kb * 4 + quad];

      floatx4 acc = {0.f, 0.f, 0.f, 0.f};
      const uint4* wl = (const uint4*)Wlds;
#pragma unroll
      for (int kb = 0; kb < 8; ++kb) {
        const uint4 braw = wl[(kb * 4 + quad) * 64 + wave * 16 + lcol];
        acc = __builtin_amdgcn_mfma_f32_16x16x32_bf16(
            __builtin_bit_cast(bf16x8, araw[kb]),
            __builtin_bit_cast(bf16x8, braw), acc, 0, 0, 0);
      }

      // C layout: col=lane&15, row=quad*4+r
#pragma unroll
      for (int r = 0; r < 4; ++r) {
        const unsigned orow = mt * 16u + (unsigned)(quad * 4 + r);
        if (orow < cnt) {
          const unsigned b_o = ordt[st + orow];
          Pn[(size_t)b_o * QD + c * CPC + wave * 16 + lcol] = f32_to_bf16(acc[r]);
        }
      }
    }

    __syncthreads();  // all waves' stores for this wg's rows done (vmcnt drained)
    __builtin_amdgcn_fence(__ATOMIC_RELEASE, "agent");
    for (unsigned i = tid; i < cnt; i += 256) {
      const unsigned b = ordt[st + i];
      __hip_atomic_fetch_add(&flags[(size_t)t * BD + b], 1u,
                             __ATOMIC_RELAXED, __HIP_MEMORY_SCOPE_AGENT);
    }
  }
}

// K5: out[b] = log(sum_q P_T[b][q] * exp(final[q])) + T*ln(256)
__global__ void k_final(const unsigned short* __restrict__ Pf, const float* __restrict__ fin,
                        float* __restrict__ out) {
  __shared__ float red[256];
  const int b = blockIdx.x, tid = threadIdx.x;
  union { unsigned u; float f; } cv;
  cv.u = ((unsigned)Pf[(size_t)b * QD + tid]) << 16;
  red[tid] = cv.f * __expf(fin[tid]);
  __syncthreads();
  for (int sft = 128; sft > 0; sft >>= 1) {
    if (tid < sft) red[tid] += red[tid + sft];
    __syncthreads();
  }
  if (tid == 0) out[b] = logf(red[0]) + (float)TD * logf(256.0f);
}

extern "C" void kernel_launch(void* const* d_in, const int* in_sizes, int n_in,
                              void* d_out, int out_size, void* d_ws, size_t ws_size,
                              hipStream_t stream) {
  const float* A    = (const float*)d_in[0];
  const float* init = (const float*)d_in[1];
  const float* fin  = (const float*)d_in[2];
  const int*   xs   = (const int*)d_in[3];
  float* out = (float*)d_out;

  char* ws = (char*)d_ws;
  unsigned short* Wrep = (unsigned short*)ws;                               // 16 MB
  unsigned short* Pa   = (unsigned short*)(ws + (16u << 20));               // 512 KB
  unsigned short* Pb   = (unsigned short*)(ws + (16u << 20) + (512u << 10));// 512 KB
  unsigned* flags      = (unsigned*)(ws + (17u << 20));                     // 512 KB
  unsigned* order      = (unsigned*)(ws + (17u << 20) + (512u << 10));      // 512 KB
  unsigned* start      = (unsigned*)(ws + (18u << 20));                     // 64 KB
  unsigned* count      = (unsigned*)(ws + (18u << 20) + (64u << 10));       // 64 KB

  k_repack<<<dim3(SD * 8), dim3(256), 0, stream>>>(A, Wrep);
  k_init<<<dim3(1024), dim3(256), 0, stream>>>(init, Pa, flags);
  k_sort<<<dim3(TD), dim3(256), 0, stream>>>(xs, order, start, count);

  void* args[] = {&Wrep, &Pa, &Pb, &flags, &order, &start, &count};
  hipLaunchCooperativeKernel((const void*)k_fwd, dim3(512), dim3(256), args, 0, stream);

  k_final<<<dim3(BD), dim3(256), 0, stream>>>(Pa, fin, out);
}

// Round 2
// 3642.777 us; speedup vs baseline: 2.0852x; 2.0852x over previous
//
#include <hip/hip_runtime.h>

#define QD 256   // states
#define SD 128   // symbols
#define BD 1024  // batch
#define TD 128   // time steps
#define NC 4     // column chunks per symbol
#define CPC 64   // columns per chunk

typedef __bf16 bf16x8 __attribute__((ext_vector_type(8)));
typedef float floatx4 __attribute__((ext_vector_type(4)));

__device__ inline unsigned short f32_to_bf16(float f) {
  union { float f; unsigned u; } v; v.f = f;
  unsigned u = v.u + 0x7fffu + ((v.u >> 16) & 1u);  // round-to-nearest-even
  return (unsigned short)(u >> 16);
}

// K1: repack A[qf][s][qt] -> Wrep in per-(symbol,chunk) MFMA B-fragment order.
// W = exp(A)/256 (per-step rescale folded in; out += T*ln(256)).
__global__ void k_repack(const float* __restrict__ A, unsigned short* __restrict__ Wrep) {
  __shared__ float tile[32][QD];
  const int bid = blockIdx.x;
  const int s = bid >> 3, kb = bid & 7;
  const int tid = threadIdx.x;
  for (int r = 0; r < 32; ++r)
    tile[r][tid] = A[(size_t)(kb * 32 + r) * (SD * QD) + (size_t)s * QD + tid];
  __syncthreads();
  for (int g = tid; g < 1024; g += 256) {
    const int c = g >> 8, quad = (g >> 6) & 3, n = g & 63;
    unsigned short out8[8];
#pragma unroll
    for (int j = 0; j < 8; ++j) {
      float v = __expf(tile[quad * 8 + j][c * 64 + n]) * 0.00390625f;
      out8[j] = f32_to_bf16(v);
    }
    size_t off = (size_t)(s * NC + c) * 16384 + (size_t)((kb * 4 + quad) * 64 + n) * 8;
    *(uint4*)(Wrep + off) = *(uint4*)out8;
  }
}

// K2: P0 rows = broadcast(init) in bf16, zero flags.
// NOTE: P0/flags are later accessed with sc1 (memory-side coherent) ops; the
// end-of-dispatch release flushes these ordinary stores to memory, so k_fwd's
// coherent accesses see them.
__global__ void k_init(const float* __restrict__ init, unsigned short* __restrict__ P0,
                       unsigned* __restrict__ flags) {
  const int i = blockIdx.x * 256 + threadIdx.x;
  if (i < BD * QD) P0[i] = f32_to_bf16(init[i & (QD - 1)]);
  if (i < TD * BD) flags[i] = 0u;
}

// K3: per-timestep counting sort of batch indices by symbol.
__global__ void k_sort(const int* __restrict__ xs, unsigned* __restrict__ order,
                       unsigned* __restrict__ start, unsigned* __restrict__ count) {
  __shared__ unsigned hist[SD];
  __shared__ unsigned cur[SD];
  const int t = blockIdx.x, tid = threadIdx.x;
  if (tid < SD) hist[tid] = 0u;
  __syncthreads();
  int sym[4];
  for (int r = 0; r < 4; ++r) {
    const int b = tid + 256 * r;
    sym[r] = xs[(size_t)b * TD + t];
    atomicAdd(&hist[sym[r]], 1u);
  }
  __syncthreads();
  if (tid == 0) {
    unsigned acc = 0;
    for (int s2 = 0; s2 < SD; ++s2) {
      cur[s2] = acc; start[t * SD + s2] = acc; count[t * SD + s2] = hist[s2];
      acc += hist[s2];
    }
  }
  __syncthreads();
  for (int r = 0; r < 4; ++r) {
    const int b = tid + 256 * r;
    const unsigned pos = atomicAdd(&cur[sym[r]], 1u);
    order[(size_t)t * BD + pos] = (unsigned)b;
  }
}

// K4: cooperative dataflow forward, FENCE-FREE protocol.
// All P communication uses relaxed agent-scope atomics (sc1: memory-side
// coherent point, no L1/L2 allocate) -> no buffer_wbl2 / buffer_inv ever.
// Ordering: producer stores (sc1) drained by __syncthreads' vmcnt(0), THEN
// flag RMW (sc1, memory-side). Consumer: control-dependent poll exit, then
// sc1 loads that bypass stale caches. The flag chain still serializes
// double-buffer reuse exactly as in R0 (which passed).
__global__ void __launch_bounds__(256, 2) k_fwd(
    const unsigned short* __restrict__ Wrep,
    unsigned short* __restrict__ Pa, unsigned short* __restrict__ Pb,
    unsigned* __restrict__ flags,
    const unsigned* __restrict__ order, const unsigned* __restrict__ start,
    const unsigned* __restrict__ count) {
  __shared__ unsigned short Wlds[16384];  // 32 KB
  const int bid = blockIdx.x;
  const int sid = bid >> 2, c = bid & 3;
  const int tid = threadIdx.x;
  const int wave = tid >> 6, lane = tid & 63;
  const int quad = lane >> 4, lcol = lane & 15;

  {
    const uint4* src = (const uint4*)(Wrep + (size_t)(sid * NC + c) * 16384);
    uint4* dst = (uint4*)Wlds;
    for (int i = tid; i < 2048; i += 256) dst[i] = src[i];
  }
  __syncthreads();

  for (int t = 0; t < TD; ++t) {
    const unsigned cnt = count[t * SD + sid];
    const unsigned st = start[t * SD + sid];
    const unsigned short* Pc = (t & 1) ? Pb : Pa;
    unsigned short* Pn = (t & 1) ? Pa : Pb;
    const unsigned* ordt = order + (size_t)t * BD;

    for (unsigned mt = 0; mt * 16u < cnt; ++mt) {
      const unsigned ridx = mt * 16u + (unsigned)lcol;
      const unsigned aidx = (ridx < cnt) ? ridx : 0u;  // OOB lanes compute garbage, not stored
      const unsigned b_a = ordt[st + aidx];

      if (t > 0) {  // wait for all 4 chunk-producers of step t-1 for row b_a
        const unsigned* fl = flags + (size_t)(t - 1) * BD + b_a;
        while (true) {
          unsigned f = __hip_atomic_load(fl, __ATOMIC_RELAXED, __HIP_MEMORY_SCOPE_AGENT);
          if (__ballot(f < 4u) == 0ull) break;
          __builtin_amdgcn_s_sleep(1);
        }
        asm volatile("" ::: "memory");  // compiler ordering only; no HW cache op
      }

      // A-fragment: lane holds P[row=lcol][k=kb*32+quad*8+j] as 32 coherent dwords
      unsigned araw[32];
      const unsigned* prow = (const unsigned*)(Pc + (size_t)b_a * QD) + quad * 4;
#pragma unroll
      for (int kb = 0; kb < 8; ++kb) {
#pragma unroll
        for (int d = 0; d < 4; ++d)
          araw[kb * 4 + d] = __hip_atomic_load(prow + kb * 16 + d,
                                               __ATOMIC_RELAXED, __HIP_MEMORY_SCOPE_AGENT);
      }

      floatx4 acc = {0.f, 0.f, 0.f, 0.f};
      const uint4* wl = (const uint4*)Wlds;
#pragma unroll
      for (int kb = 0; kb < 8; ++kb) {
        uint4 av;
        av.x = araw[kb * 4 + 0]; av.y = araw[kb * 4 + 1];
        av.z = araw[kb * 4 + 2]; av.w = araw[kb * 4 + 3];
        const uint4 braw = wl[(kb * 4 + quad) * 64 + wave * 16 + lcol];
        acc = __builtin_amdgcn_mfma_f32_16x16x32_bf16(
            __builtin_bit_cast(bf16x8, av),
            __builtin_bit_cast(bf16x8, braw), acc, 0, 0, 0);
      }

      // C layout: col=lane&15, row=quad*4+r ; coherent 16-bit stores
#pragma unroll
      for (int r = 0; r < 4; ++r) {
        const unsigned orow = mt * 16u + (unsigned)(quad * 4 + r);
        if (orow < cnt) {
          const unsigned b_o = ordt[st + orow];
          unsigned short hv = f32_to_bf16(acc[r]);
          __hip_atomic_store(Pn + (size_t)b_o * QD + c * CPC + wave * 16 + lcol, hv,
                             __ATOMIC_RELAXED, __HIP_MEMORY_SCOPE_AGENT);
        }
      }
    }

    __syncthreads();  // emits s_waitcnt vmcnt(0): sc1 stores are globally visible
    for (unsigned i = tid; i < cnt; i += 256) {
      const unsigned b = ordt[st + i];
      __hip_atomic_fetch_add(&flags[(size_t)t * BD + b], 1u,
                             __ATOMIC_RELAXED, __HIP_MEMORY_SCOPE_AGENT);
    }
  }
}

// K5: out[b] = log(sum_q P_T[b][q] * exp(final[q])) + T*ln(256)
__global__ void k_final(const unsigned short* __restrict__ Pf, const float* __restrict__ fin,
                        float* __restrict__ out) {
  __shared__ float red[256];
  const int b = blockIdx.x, tid = threadIdx.x;
  union { unsigned u; float f; } cv;
  cv.u = ((unsigned)Pf[(size_t)b * QD + tid]) << 16;
  red[tid] = cv.f * __expf(fin[tid]);
  __syncthreads();
  for (int sft = 128; sft > 0; sft >>= 1) {
    if (tid < sft) red[tid] += red[tid + sft];
    __syncthreads();
  }
  if (tid == 0) out[b] = logf(red[0]) + (float)TD * logf(256.0f);
}

extern "C" void kernel_launch(void* const* d_in, const int* in_sizes, int n_in,
                              void* d_out, int out_size, void* d_ws, size_t ws_size,
                              hipStream_t stream) {
  const float* A    = (const float*)d_in[0];
  const float* init = (const float*)d_in[1];
  const float* fin  = (const float*)d_in[2];
  const int*   xs   = (const int*)d_in[3];
  float* out = (float*)d_out;

  char* ws = (char*)d_ws;
  unsigned short* Wrep = (unsigned short*)ws;                               // 16 MB
  unsigned short* Pa   = (unsigned short*)(ws + (16u << 20));               // 512 KB
  unsigned short* Pb   = (unsigned short*)(ws + (16u << 20) + (512u << 10));// 512 KB
  unsigned* flags      = (unsigned*)(ws + (17u << 20));                     // 512 KB
  unsigned* order      = (unsigned*)(ws + (17u << 20) + (512u << 10));      // 512 KB
  unsigned* start      = (unsigned*)(ws + (18u << 20));                     // 64 KB
  unsigned* count      = (unsigned*)(ws + (18u << 20) + (64u << 10));       // 64 KB

  k_repack<<<dim3(SD * 8), dim3(256), 0, stream>>>(A, Wrep);
  k_init<<<dim3(1024), dim3(256), 0, stream>>>(init, Pa, flags);
  k_sort<<<dim3(TD), dim3(256), 0, stream>>>(xs, order, start, count);

  void* args[] = {&Wrep, &Pa, &Pb, &flags, &order, &start, &count};
  hipLaunchCooperativeKernel((const void*)k_fwd, dim3(512), dim3(256), args, 0, stream);

  k_final<<<dim3(BD), dim3(256), 0, stream>>>(Pa, fin, out);
}

// Round 3
// 898.415 us; speedup vs baseline: 8.4550x; 4.0547x over previous
//
#include <hip/hip_runtime.h>

#define QD 256   // states
#define SD 128   // symbols
#define BD 1024  // batch
#define TD 128   // time steps
// P stored as fp8 e4m3, scale: P'' ~ 0.5; W' = exp(A)/4; per-step acc *= 2^-6
// => P''_t = P_true_t * 2^-(8t+1); out += (8*T+1)*ln2.

typedef float floatx4 __attribute__((ext_vector_type(4)));

__device__ inline unsigned char f32_to_e4m3(float f) {
  // valid for positive normal inputs in [2^-6, 448); RNE
  union { float f; unsigned u; } v; v.f = f;
  int exp = (int)((v.u >> 23) & 0xffu) - 127 + 7;
  unsigned man = v.u & 0x7fffffu;
  unsigned m3 = man >> 20;
  unsigned rest = man & 0xfffffu;
  if (rest > 0x80000u || (rest == 0x80000u && (m3 & 1u))) ++m3;
  if (m3 == 8u) { m3 = 0u; ++exp; }
  return (unsigned char)((exp << 3) | m3);
}

// K1: repack A[qf][s][qt] -> Wrep fp8 in per-(symbol,half) MFMA B-fragment order.
// Per (s,c) 32KB block: byte ((ntile*8+kb)*64 + quad*16 + n)*8 + j holds
// W'[k=kb*32+quad*8+j][col = c*128 + ntile*16 + n],  W' = exp(A)/4.
__global__ void k_repack(const float* __restrict__ A, unsigned long long* __restrict__ Wrep) {
  __shared__ float tile[32][QD];
  const int bid = blockIdx.x;
  const int s = bid >> 3, kb = bid & 7;
  const int tid = threadIdx.x;
  for (int r = 0; r < 32; ++r)
    tile[r][tid] = A[(size_t)(kb * 32 + r) * (SD * QD) + (size_t)s * QD + tid];
  __syncthreads();
  for (int g = tid; g < 1024; g += 256) {
    const int c = g >> 9, r9 = g & 511;
    const int ntile = r9 >> 6, rem = r9 & 63, quad = rem >> 4, n = rem & 15;
    const int col = c * 128 + ntile * 16 + n;
    unsigned long long w = 0ull;
#pragma unroll
    for (int j = 0; j < 8; ++j) {
      float v = __expf(tile[quad * 8 + j][col]) * 0.25f;
      w |= (unsigned long long)f32_to_e4m3(v) << (8 * j);
    }
    Wrep[(size_t)(s * 2 + c) * 4096 + (size_t)((ntile * 8 + kb) * 64 + quad * 16 + n)] = w;
  }
}

// K2: P0 = 0.5*init in e4m3 (one-hot -> 0x30 at state 0), zero epoch flags.
__global__ void k_init(const float* __restrict__ init, unsigned char* __restrict__ P0,
                       unsigned* __restrict__ flags) {
  const int i = blockIdx.x * 256 + threadIdx.x;
  if (i < BD * QD) {
    float v = init[i & (QD - 1)];
    P0[i] = (v > 0.f) ? f32_to_e4m3(0.5f * v) : (unsigned char)0;
  }
  if (i < BD) flags[i] = 0u;
}

// K3: per-timestep counting sort of batch indices by symbol.
__global__ void k_sort(const int* __restrict__ xs, unsigned* __restrict__ order,
                       unsigned* __restrict__ start, unsigned* __restrict__ count) {
  __shared__ unsigned hist[SD];
  __shared__ unsigned cur[SD];
  const int t = blockIdx.x, tid = threadIdx.x;
  if (tid < SD) hist[tid] = 0u;
  __syncthreads();
  int sym[4];
  for (int r = 0; r < 4; ++r) {
    const int b = tid + 256 * r;
    sym[r] = xs[(size_t)b * TD + t];
    atomicAdd(&hist[sym[r]], 1u);
  }
  __syncthreads();
  if (tid == 0) {
    unsigned acc = 0;
    for (int s2 = 0; s2 < SD; ++s2) {
      cur[s2] = acc; start[t * SD + s2] = acc; count[t * SD + s2] = hist[s2];
      acc += hist[s2];
    }
  }
  __syncthreads();
  for (int r = 0; r < 4; ++r) {
    const int b = tid + 256 * r;
    const unsigned pos = atomicAdd(&cur[sym[r]], 1u);
    order[(size_t)t * BD + pos] = (unsigned)b;
  }
}

// K4: cooperative dataflow forward, fp8, 256 blocks = (symbol, col-half).
// W half (128 cols) lives in LDS all 128 steps. Per step: poll epoch flags
// (>= 2t), stage 16-row P tile into LDS via u64 sc1 loads (once, shared by
// all 4 waves), fp8 MFMA, epilogue -> LDS -> u64 sc1 stores, then
// flags[b] += 1 per half-producer (reaches 2(t+1) when row fully written).
__global__ void __launch_bounds__(256, 2) k_fwd(
    const unsigned long long* __restrict__ Wrep,
    unsigned long long* __restrict__ Pa, unsigned long long* __restrict__ Pb,
    unsigned* __restrict__ flags,
    const unsigned* __restrict__ order, const unsigned* __restrict__ start,
    const unsigned* __restrict__ count) {
  __shared__ unsigned long long Wl[4096];   // 32 KB fp8 B-fragments
  __shared__ unsigned long long PinL[512];  // 16 rows x 256 B (swizzled u64 chunks)
  __shared__ unsigned long long PoutL[256]; // 16 rows x 128 B (swizzled)
  const int bid = blockIdx.x;
  const int sid = bid >> 1, c = bid & 1;
  const int tid = threadIdx.x;
  const int wave = tid >> 6, lane = tid & 63;
  const int quad = lane >> 4, lcol = lane & 15;

  for (int i = tid; i < 4096; i += 256)
    Wl[i] = Wrep[(size_t)(sid * 2 + c) * 4096 + i];
  __syncthreads();

  for (int t = 0; t < TD; ++t) {
    const unsigned cnt = count[t * SD + sid];
    const unsigned st = start[t * SD + sid];
    const unsigned long long* Pc = (t & 1) ? Pb : Pa;
    unsigned long long* Pn = (t & 1) ? Pa : Pb;
    const unsigned* ordt = order + (size_t)t * BD;
    const unsigned need = 2u * (unsigned)t;

    for (unsigned mt = 0; mt * 16u < cnt; ++mt) {
      const int rtile = (int)((cnt - mt * 16u < 16u) ? (cnt - mt * 16u) : 16u);

      // stage-in: poll + load, spread over all 256 threads (disjoint chunks)
      for (int j = tid; j < rtile * 32; j += 256) {
        const int row = j >> 5, cu = j & 31;
        const unsigned b = ordt[st + mt * 16u + (unsigned)row];
        if (t > 0) {
          while (__hip_atomic_load(&flags[b], __ATOMIC_RELAXED,
                                   __HIP_MEMORY_SCOPE_AGENT) < need)
            __builtin_amdgcn_s_sleep(1);
          asm volatile("" ::: "memory");
        }
        unsigned long long v = __hip_atomic_load(&Pc[(size_t)b * 32 + cu],
                                                 __ATOMIC_RELAXED, __HIP_MEMORY_SCOPE_AGENT);
        PinL[row * 32 + (cu ^ row)] = v;
      }
      __syncthreads();

      // A-fragments from LDS (swizzled), fp8 MFMA over K=256, 2 ntiles/wave
      unsigned long long a8[8];
#pragma unroll
      for (int kb = 0; kb < 8; ++kb)
        a8[kb] = PinL[lcol * 32 + ((kb * 4 + quad) ^ lcol)];

      floatx4 acc0 = {0.f, 0.f, 0.f, 0.f}, acc1 = {0.f, 0.f, 0.f, 0.f};
#pragma unroll
      for (int kb = 0; kb < 8; ++kb) {
        const unsigned long long b0 = Wl[((wave * 2 + 0) * 8 + kb) * 64 + quad * 16 + lcol];
        const unsigned long long b1 = Wl[((wave * 2 + 1) * 8 + kb) * 64 + quad * 16 + lcol];
        acc0 = __builtin_amdgcn_mfma_f32_16x16x32_fp8_fp8((long)a8[kb], (long)b0, acc0, 0, 0, 0);
        acc1 = __builtin_amdgcn_mfma_f32_16x16x32_fp8_fp8((long)a8[kb], (long)b1, acc1, 0, 0, 0);
      }

      // epilogue: C layout col=lane&15, row=quad*4+r; scale 2^-6, fp8, to LDS
      unsigned char* PoutB = (unsigned char*)PoutL;
#pragma unroll
      for (int nt = 0; nt < 2; ++nt) {
        const int colL = (wave * 2 + nt) * 16 + lcol;
        const int chunk = colL >> 3;
        const floatx4& a = nt ? acc1 : acc0;
#pragma unroll
        for (int r = 0; r < 4; ++r) {
          const int orow = quad * 4 + r;
          if (orow < rtile)
            PoutB[orow * 128 + ((chunk ^ orow) << 3) + (colL & 7)] =
                f32_to_e4m3(a[r] * 0.015625f);
        }
      }
      __syncthreads();

      // stage-out: u64 sc1 stores of this half-row
      for (int j = tid; j < rtile * 16; j += 256) {
        const int row = j >> 4, cu = j & 15;
        const unsigned b = ordt[st + mt * 16u + (unsigned)row];
        const unsigned long long v = PoutL[row * 16 + (cu ^ row)];
        __hip_atomic_store(&Pn[(size_t)b * 32 + c * 16 + cu], v,
                           __ATOMIC_RELAXED, __HIP_MEMORY_SCOPE_AGENT);
      }
      __syncthreads();  // drains vmcnt: stores globally visible; LDS reusable
    }

    // publish epochs: +1 per half-producer (row complete at 2(t+1))
    for (unsigned i = tid; i < cnt; i += 256)
      __hip_atomic_fetch_add(&flags[ordt[st + i]], 1u,
                             __ATOMIC_RELAXED, __HIP_MEMORY_SCOPE_AGENT);
  }
}

// K5: out[b] = log(sum_q P''_T[b][q] * exp(final[q])) + (8*T+1)*ln2
__global__ void k_final(const unsigned char* __restrict__ Pf, const float* __restrict__ fin,
                        float* __restrict__ out) {
  __shared__ float red[256];
  const int b = blockIdx.x, tid = threadIdx.x;
  const unsigned char x = Pf[(size_t)b * QD + tid];
  const int E = x >> 3, m = x & 7;
  const float p = (E == 0) ? ldexpf((float)m, -9) : ldexpf(1.0f + 0.125f * (float)m, E - 7);
  red[tid] = p * __expf(fin[tid]);
  __syncthreads();
  for (int sft = 128; sft > 0; sft >>= 1) {
    if (tid < sft) red[tid] += red[tid + sft];
    __syncthreads();
  }
  if (tid == 0) out[b] = logf(red[0]) + 1025.0f * 0.6931471805599453f;
}

extern "C" void kernel_launch(void* const* d_in, const int* in_sizes, int n_in,
                              void* d_out, int out_size, void* d_ws, size_t ws_size,
                              hipStream_t stream) {
  const float* A    = (const float*)d_in[0];
  const float* init = (const float*)d_in[1];
  const float* fin  = (const float*)d_in[2];
  const int*   xs   = (const int*)d_in[3];
  float* out = (float*)d_out;

  char* ws = (char*)d_ws;
  unsigned long long* Wrep = (unsigned long long*)ws;                        // 8 MB
  unsigned long long* Pa   = (unsigned long long*)(ws + (8u << 20));         // 256 KB
  unsigned long long* Pb   = (unsigned long long*)(ws + (8u << 20) + (256u << 10)); // 256 KB
  unsigned* flags          = (unsigned*)(ws + (9u << 20));                   // 4 KB
  unsigned* order          = (unsigned*)(ws + (9u << 20) + (64u << 10));     // 512 KB
  unsigned* start          = (unsigned*)(ws + (10u << 20));                  // 64 KB
  unsigned* count          = (unsigned*)(ws + (10u << 20) + (64u << 10));    // 64 KB

  k_repack<<<dim3(SD * 8), dim3(256), 0, stream>>>(A, Wrep);
  k_init<<<dim3(1024), dim3(256), 0, stream>>>(init, (unsigned char*)Pa, flags);
  k_sort<<<dim3(TD), dim3(256), 0, stream>>>(xs, order, start, count);

  void* args[] = {&Wrep, &Pa, &Pb, &flags, &order, &start, &count};
  hipLaunchCooperativeKernel((const void*)k_fwd, dim3(256), dim3(256), args, 0, stream);

  k_final<<<dim3(BD), dim3(256), 0, stream>>>((const unsigned char*)Pa, fin, out);
}